// Round 4
// baseline (465.871 us; speedup 1.0000x reference)
//
#include <hip/hip_runtime.h>
#include <hip/hip_cooperative_groups.h>
#include <math.h>

namespace cg = cooperative_groups;

#define H 1024
#define MAXLEN 128
#define VOCAB 50257
#define NT 256
#define NB_MAX 1024
#define NB_OUT ((VOCAB + 3) / 4)   // fallback path: 12565 blocks, 4 rows each

__device__ inline float wave_reduce_sum(float v) {
    #pragma unroll
    for (int off = 32; off > 0; off >>= 1) v += __shfl_down(v, off);
    return v;  // lane 0 holds the sum
}

__device__ inline float dot4(float4 a, float4 b) {
    return a.x * b.x + a.y * b.y + a.z * b.z + a.w * b.w;
}

// ============================ Cooperative fused path ============================
__global__ void __launch_bounds__(NT, 4) k_fused(
    const int* x, const float* h, const float* enc, const float* emb,
    const float* W_attn, const float* b_attn,
    const float* W_comb, const float* b_comb,
    const float* w_ih, const float* w_hh, const float* b_ih, const float* b_hh,
    const float* W_out, const float* b_out,
    float* out, float* out_h, float* out_attn,
    float* logits128, float* attn_applied, float* g_vec,
    float* pmax, float* psum)
{
    cg::grid_group grid = cg::this_grid();
    const int bid = blockIdx.x, t = threadIdx.x;
    const int nb = gridDim.x;
    const int lane = t & 63, wid = t >> 6;
    __shared__ float red[4];
    __shared__ float red6[4][6];
    __shared__ float buf[MAXLEN];
    __shared__ float wsm[MAXLEN];
    __shared__ float lm[4], lssum[4];
    __shared__ float csh;

    // ---- Phase 1: attn logits[i] = dot(concat(e,h0), W_attn[i]) + b_attn[i]
    for (int row = bid; row < MAXLEN; row += nb) {
        const float4* w4 = (const float4*)(W_attn + row * (2 * H));
        const float4* e4 = (const float4*)(emb + (long long)x[0] * H);
        const float4* h4 = (const float4*)h;
        float acc = 0.f;
        #pragma unroll
        for (int i = 0; i < 2; i++) {
            int idx = t + i * NT;  // float4 index into 512-wide row
            float4 wv = w4[idx];
            float4 cv = (idx < 256) ? e4[idx] : h4[idx - 256];
            acc += dot4(wv, cv);
        }
        acc = wave_reduce_sum(acc);
        if (lane == 0) red[wid] = acc;
        __syncthreads();
        if (t == 0) logits128[row] = red[0] + red[1] + red[2] + red[3] + b_attn[row];
        __syncthreads();
    }
    grid.sync();

    // ---- Phase 2: softmax over 128 + attn_applied[j] = sum_k w[k]*enc[k][j]
    {
        if (t < MAXLEN) buf[t] = logits128[t];
        __syncthreads();
        float m = -INFINITY;
        #pragma unroll 8
        for (int k = 0; k < MAXLEN; k++) m = fmaxf(m, buf[k]);
        if (t < MAXLEN) wsm[t] = expf(buf[t] - m);
        __syncthreads();
        float s = 0.f;
        #pragma unroll 8
        for (int k = 0; k < MAXLEN; k++) s += wsm[k];
        float inv = 1.f / s;
        for (int jb = bid; jb < H / NT; jb += nb) {
            int j = jb * NT + t;
            float acc = 0.f;
            #pragma unroll 8
            for (int k = 0; k < MAXLEN; k++) acc += wsm[k] * enc[k * H + j];
            attn_applied[j] = acc * inv;
        }
        if (bid == 0 && t < MAXLEN) out_attn[t] = wsm[t] * inv;
    }
    grid.sync();

    // ---- Phase 3: g[row] = relu(dot(concat(e, attn_applied), W_comb[row]) + b)
    for (int rb = bid; rb < H / 4; rb += nb) {
        int row = rb * 4 + wid;
        const float4* w4 = (const float4*)(W_comb + (long long)row * (2 * H));
        const float4* e4 = (const float4*)(emb + (long long)x[0] * H);
        const float4* a4 = (const float4*)attn_applied;
        float acc = 0.f;
        #pragma unroll
        for (int i = 0; i < 8; i++) {
            int idx = lane + i * 64;
            float4 wv = w4[idx];
            float4 cv = (idx < 256) ? e4[idx] : a4[idx - 256];
            acc += dot4(wv, cv);
        }
        acc = wave_reduce_sum(acc);
        if (lane == 0) g_vec[row] = fmaxf(acc + b_comb[row], 0.f);
    }
    grid.sync();

    // ---- Phase 4: GRU fused — block handles output j: all 6 dots + gates -> h_new[j]
    for (int j = bid; j < H; j += nb) {
        const float4* g4 = (const float4*)g_vec;
        const float4* h4 = (const float4*)h;
        float4 vg = g4[t];
        float4 vh = h4[t];
        float a[6];
        #pragma unroll
        for (int gt = 0; gt < 3; gt++) {
            const float4* wi = (const float4*)(w_ih + (long long)(j + gt * H) * H);
            const float4* wh = (const float4*)(w_hh + (long long)(j + gt * H) * H);
            a[gt]     = dot4(wi[t], vg);
            a[3 + gt] = dot4(wh[t], vh);
        }
        #pragma unroll
        for (int k = 0; k < 6; k++) {
            float v = a[k];
            #pragma unroll
            for (int off = 32; off > 0; off >>= 1) v += __shfl_down(v, off);
            if (lane == 0) red6[wid][k] = v;
        }
        __syncthreads();
        if (t == 0) {
            float d[6];
            #pragma unroll
            for (int k = 0; k < 6; k++)
                d[k] = red6[0][k] + red6[1][k] + red6[2][k] + red6[3][k];
            float gi_r = d[0] + b_ih[j];
            float gi_z = d[1] + b_ih[j + H];
            float gi_n = d[2] + b_ih[j + 2 * H];
            float gh_r = d[3] + b_hh[j];
            float gh_z = d[4] + b_hh[j + H];
            float gh_n = d[5] + b_hh[j + 2 * H];
            float r = 1.f / (1.f + expf(-(gi_r + gh_r)));
            float z = 1.f / (1.f + expf(-(gi_z + gh_z)));
            float n = tanhf(gi_n + r * gh_n);
            out_h[j] = (1.f - z) * n + z * h[j];
        }
        __syncthreads();
    }
    grid.sync();

    // ---- Phase 5: out matvec (wave per row, strided) + per-block LSE partials
    {
        const float4* h4 = (const float4*)out_h;
        float4 hreg[4];
        #pragma unroll
        for (int i = 0; i < 4; i++) hreg[i] = h4[lane + i * 64];
        int wave_gid = bid * 4 + wid;
        float mrun = -INFINITY, srun = 0.f;  // lane-0-valid
        for (int row = wave_gid; row < VOCAB; row += nb * 4) {
            const float4* w4 = (const float4*)(W_out + (long long)row * H);
            float acc = 0.f;
            #pragma unroll
            for (int i = 0; i < 4; i++) acc += dot4(w4[lane + i * 64], hreg[i]);
            acc = wave_reduce_sum(acc);
            if (lane == 0) {
                float logit = acc + b_out[row];
                out[row] = logit;
                if (logit > mrun) {
                    srun = srun * expf(mrun - logit) + 1.f;
                    mrun = logit;
                } else {
                    srun += expf(logit - mrun);
                }
            }
        }
        if (lane == 0) { lm[wid] = mrun; lssum[wid] = srun; }
        __syncthreads();
        if (t == 0) {
            float m = fmaxf(fmaxf(lm[0], lm[1]), fmaxf(lm[2], lm[3]));
            float s = 0.f;
            #pragma unroll
            for (int i = 0; i < 4; i++)
                if (lm[i] != -INFINITY) s += lssum[i] * expf(lm[i] - m);
            pmax[bid] = m;
            psum[bid] = s;
        }
    }
    grid.sync();

    // ---- Phase 6: every block redundantly merges partials, then subtracts
    {
        float m = -INFINITY;
        for (int i = t; i < nb; i += NT) m = fmaxf(m, pmax[i]);
        #pragma unroll
        for (int off = 32; off > 0; off >>= 1) m = fmaxf(m, __shfl_down(m, off));
        if (lane == 0) red[wid] = m;
        __syncthreads();
        if (t == 0) red[0] = fmaxf(fmaxf(red[0], red[1]), fmaxf(red[2], red[3]));
        __syncthreads();
        float M = red[0];
        float s = 0.f;
        for (int i = t; i < nb; i += NT) s += psum[i] * expf(pmax[i] - M);
        s = wave_reduce_sum(s);
        if (lane == 0) lssum[wid] = s;
        __syncthreads();
        if (t == 0) csh = M + logf(lssum[0] + lssum[1] + lssum[2] + lssum[3]);
        __syncthreads();
        float c = csh;
        for (int v = bid * NT + t; v < VOCAB; v += nb * NT) out[v] -= c;
    }
}

// ============================ Fallback path (round-2, verified 74 us) ============================
__global__ void k_attn_logits(const int* x, const float* h, const float* emb,
                              const float* W_attn, const float* b_attn, float* logits) {
    const int row = blockIdx.x;
    const float4* w4 = (const float4*)(W_attn + row * (2 * H));
    const float4* e4 = (const float4*)(emb + (long long)x[0] * H);
    const float4* h4 = (const float4*)h;
    float acc = 0.f;
    int t = threadIdx.x;
    #pragma unroll
    for (int i = 0; i < 2; i++) {
        int idx = t + i * 256;
        float4 wv = w4[idx];
        float4 cv = (idx < 256) ? e4[idx] : h4[idx - 256];
        acc += dot4(wv, cv);
    }
    __shared__ float red[4];
    int lane = t & 63, wid = t >> 6;
    acc = wave_reduce_sum(acc);
    if (lane == 0) red[wid] = acc;
    __syncthreads();
    if (t == 0) logits[row] = red[0] + red[1] + red[2] + red[3] + b_attn[row];
}

__global__ void k_attn_sm_apply(const float* logits, const float* enc,
                                float* attn_applied, float* out_attn) {
    __shared__ float buf[MAXLEN];
    __shared__ float w[MAXLEN];
    int t = threadIdx.x;
    if (t < MAXLEN) buf[t] = logits[t];
    __syncthreads();
    float m = -INFINITY;
    #pragma unroll 8
    for (int k = 0; k < MAXLEN; k++) m = fmaxf(m, buf[k]);
    if (t < MAXLEN) w[t] = expf(buf[t] - m);
    __syncthreads();
    float s = 0.f;
    #pragma unroll 8
    for (int k = 0; k < MAXLEN; k++) s += w[k];
    float inv = 1.f / s;
    int j = blockIdx.x * blockDim.x + t;
    float acc = 0.f;
    #pragma unroll 8
    for (int k = 0; k < MAXLEN; k++) acc += w[k] * enc[k * H + j];
    attn_applied[j] = acc * inv;
    if (blockIdx.x == 0 && t < MAXLEN) out_attn[t] = w[t] * inv;
}

__global__ void k_combine(const int* x, const float* emb, const float* attn_applied,
                          const float* W_comb, const float* b_comb, float* g) {
    int wid = threadIdx.x >> 6, lane = threadIdx.x & 63;
    int row = blockIdx.x * 4 + wid;
    const float4* w4 = (const float4*)(W_comb + (long long)row * (2 * H));
    const float4* e4 = (const float4*)(emb + (long long)x[0] * H);
    const float4* a4 = (const float4*)attn_applied;
    float acc = 0.f;
    #pragma unroll
    for (int i = 0; i < 8; i++) {
        int idx = lane + i * 64;
        float4 wv = w4[idx];
        float4 cv = (idx < 256) ? e4[idx] : a4[idx - 256];
        acc += dot4(wv, cv);
    }
    acc = wave_reduce_sum(acc);
    if (lane == 0) g[row] = fmaxf(acc + b_comb[row], 0.f);
}

__global__ void k_gru_mm(const float* g, const float* h,
                         const float* w_ih, const float* w_hh,
                         const float* b_ih, const float* b_hh,
                         float* gi, float* gh) {
    int wid = threadIdx.x >> 6, lane = threadIdx.x & 63;
    int gRow = blockIdx.x * 4 + wid;
    const float* vec; const float* mat; const float* bias; float* outp; int row;
    if (gRow < 3 * H) { row = gRow; vec = g; mat = w_ih; bias = b_ih; outp = gi; }
    else { row = gRow - 3 * H; vec = h; mat = w_hh; bias = b_hh; outp = gh; }
    const float4* w4 = (const float4*)(mat + (long long)row * H);
    const float4* v4 = (const float4*)vec;
    float acc = 0.f;
    #pragma unroll
    for (int i = 0; i < 4; i++) {
        int idx = lane + i * 64;
        acc += dot4(w4[idx], v4[idx]);
    }
    acc = wave_reduce_sum(acc);
    if (lane == 0) outp[row] = acc + bias[row];
}

__global__ void k_gates(const float* gi, const float* gh, const float* h, float* h_new) {
    int j = threadIdx.x;
    float r = 1.f / (1.f + expf(-(gi[j] + gh[j])));
    float z = 1.f / (1.f + expf(-(gi[j + H] + gh[j + H])));
    float n = tanhf(gi[j + 2 * H] + r * gh[j + 2 * H]);
    h_new[j] = (1.f - z) * n + z * h[j];
}

__global__ void k_out_matvec(const float* hn, const float* W_out, const float* b_out,
                             float* out, float* pmax, float* psum) {
    int wid = threadIdx.x >> 6, lane = threadIdx.x & 63;
    int row = blockIdx.x * 4 + wid;
    __shared__ float lm[4];
    float logit = -INFINITY;
    if (row < VOCAB) {
        const float4* w4 = (const float4*)(W_out + (long long)row * H);
        const float4* h4 = (const float4*)hn;
        float acc = 0.f;
        #pragma unroll
        for (int i = 0; i < 4; i++) {
            int idx = lane + i * 64;
            acc += dot4(w4[idx], h4[idx]);
        }
        acc = wave_reduce_sum(acc);
        if (lane == 0) { logit = acc + b_out[row]; out[row] = logit; }
    }
    if (lane == 0) lm[wid] = logit;
    __syncthreads();
    if (threadIdx.x == 0) {
        float m = fmaxf(fmaxf(lm[0], lm[1]), fmaxf(lm[2], lm[3]));
        float s = 0.f;
        #pragma unroll
        for (int i = 0; i < 4; i++)
            if (lm[i] != -INFINITY) s += expf(lm[i] - m);
        pmax[blockIdx.x] = m;
        psum[blockIdx.x] = s;
    }
}

__global__ void k_lse_merge(const float* pmax, const float* psum, float* c) {
    __shared__ float red[16];
    __shared__ float Msh;
    int lane = threadIdx.x & 63, wid = threadIdx.x >> 6;
    float m = -INFINITY;
    for (int i = threadIdx.x; i < NB_OUT; i += blockDim.x) m = fmaxf(m, pmax[i]);
    #pragma unroll
    for (int off = 32; off > 0; off >>= 1) m = fmaxf(m, __shfl_down(m, off));
    if (lane == 0) red[wid] = m;
    __syncthreads();
    if (threadIdx.x == 0) {
        float mm = red[0];
        for (int i = 1; i < 16; i++) mm = fmaxf(mm, red[i]);
        Msh = mm;
    }
    __syncthreads();
    float M = Msh;
    float s = 0.f;
    for (int i = threadIdx.x; i < NB_OUT; i += blockDim.x) s += psum[i] * expf(pmax[i] - M);
    s = wave_reduce_sum(s);
    if (lane == 0) red[wid] = s;
    __syncthreads();
    if (threadIdx.x == 0) {
        float ss = 0.f;
        for (int i = 0; i < 16; i++) ss += red[i];
        c[0] = M + logf(ss);
    }
}

__global__ void k_sub(float* out, const float* c) {
    int v = blockIdx.x * blockDim.x + threadIdx.x;
    if (v < VOCAB) out[v] -= c[0];
}

// ============================ launcher ============================
extern "C" void kernel_launch(void* const* d_in, const int* in_sizes, int n_in,
                              void* d_out, int out_size, void* d_ws, size_t ws_size,
                              hipStream_t stream) {
    const int*   x     = (const int*)d_in[0];
    const float* h     = (const float*)d_in[1];   // [1,1,H]
    const float* enc   = (const float*)d_in[2];   // [128,H]
    const float* emb   = (const float*)d_in[3];   // [VOCAB,H]
    const float* W_attn= (const float*)d_in[4];   // [128,2H]
    const float* b_attn= (const float*)d_in[5];
    const float* W_comb= (const float*)d_in[6];   // [H,2H]
    const float* b_comb= (const float*)d_in[7];
    const float* w_ih  = (const float*)d_in[8];   // [3H,H]
    const float* w_hh  = (const float*)d_in[9];
    const float* b_ih  = (const float*)d_in[10];
    const float* b_hh  = (const float*)d_in[11];
    const float* W_out = (const float*)d_in[12];  // [VOCAB,H]
    const float* b_out = (const float*)d_in[13];

    float* out      = (float*)d_out;              // [VOCAB] log-probs
    float* out_h    = out + VOCAB;                // [H] h_new
    float* out_attn = out + VOCAB + H;            // [128] attn_w

    float* ws          = (float*)d_ws;
    float* logits128   = ws;            // 128
    float* attn_applied= ws + 256;      // 1024
    float* g_vec       = ws + 1280;     // 1024
    float* gi          = ws + 2304;     // 3072
    float* gh          = ws + 5376;     // 3072
    float* lse_c       = ws + 8448;     // 1
    float* pmax        = ws + 9216;     // max(NB_MAX, NB_OUT)
    float* psum        = ws + 22272;    // max(NB_MAX, NB_OUT)

    // ---- Try the cooperative fused path; size grid from occupancy.
    int dev = 0;
    hipGetDevice(&dev);
    int numCU = 0;
    hipDeviceGetAttribute(&numCU, hipDeviceAttributeMultiprocessorCount, dev);
    int maxBpc = 0;
    hipOccupancyMaxActiveBlocksPerMultiprocessor(&maxBpc, (const void*)k_fused, NT, 0);
    int nb = numCU * maxBpc;
    if (nb > NB_MAX) nb = NB_MAX;

    bool coop_ok = false;
    if (nb > 0) {
        void* kargs[] = {
            (void*)&x, (void*)&h, (void*)&enc, (void*)&emb,
            (void*)&W_attn, (void*)&b_attn, (void*)&W_comb, (void*)&b_comb,
            (void*)&w_ih, (void*)&w_hh, (void*)&b_ih, (void*)&b_hh,
            (void*)&W_out, (void*)&b_out,
            (void*)&out, (void*)&out_h, (void*)&out_attn,
            (void*)&logits128, (void*)&attn_applied, (void*)&g_vec,
            (void*)&pmax, (void*)&psum
        };
        hipError_t err = hipLaunchCooperativeKernel((void*)k_fused, dim3(nb), dim3(NT),
                                                    kargs, 0, stream);
        coop_ok = (err == hipSuccess);
    }

    if (!coop_ok) {
        // Fallback: verified 8-kernel path (round 2).
        k_attn_logits<<<MAXLEN, 256, 0, stream>>>(x, h, emb, W_attn, b_attn, logits128);
        k_attn_sm_apply<<<H / 256, 256, 0, stream>>>(logits128, enc, attn_applied, out_attn);
        k_combine<<<H / 4, 256, 0, stream>>>(x, emb, attn_applied, W_comb, b_comb, g_vec);
        k_gru_mm<<<(6 * H) / 4, 256, 0, stream>>>(g_vec, h, w_ih, w_hh, b_ih, b_hh, gi, gh);
        k_gates<<<1, H, 0, stream>>>(gi, gh, h, out_h);
        k_out_matvec<<<NB_OUT, 256, 0, stream>>>(out_h, W_out, b_out, out, pmax, psum);
        k_lse_merge<<<1, 1024, 0, stream>>>(pmax, psum, lse_c);
        k_sub<<<(VOCAB + 255) / 256, 256, 0, stream>>>(out, lse_c);
    }
}

// Round 5
// 283.245 us; speedup vs baseline: 1.6448x; 1.6448x over previous
//
#include <hip/hip_runtime.h>
#include <math.h>

#define H 1024
#define MAXLEN 128
#define VOCAB 50257

#define NB_A 256        // prefix kernel: 256 blocks x 256 threads (1 block/CU guaranteed resident)
#define NT_A 256
#define NT_B 1024       // projection kernel: 16 rows (1 per wave) per block
#define ROWS_B 16
#define NB_B ((VOCAB + ROWS_B - 1) / ROWS_B)   // 3142

__device__ inline float wave_reduce_sum(float v) {
    #pragma unroll
    for (int off = 32; off > 0; off >>= 1) v += __shfl_down(v, off);
    return v;  // lane 0 holds the sum
}

__device__ inline float dot4(float4 a, float4 b) {
    return a.x * b.x + a.y * b.y + a.z * b.z + a.w * b.w;
}

// Device-scope software barrier. ctr must be zeroed before the kernel runs.
// Safe: grid (256 blocks, 1/CU min occupancy 4) is always fully resident.
__device__ inline void sw_barrier(unsigned* ctr, unsigned nb) {
    __syncthreads();
    if (threadIdx.x == 0) {
        __threadfence();  // release: make this block's writes visible device-wide
        __hip_atomic_fetch_add(ctr, 1u, __ATOMIC_ACQ_REL, __HIP_MEMORY_SCOPE_AGENT);
        while (__hip_atomic_load(ctr, __ATOMIC_ACQUIRE, __HIP_MEMORY_SCOPE_AGENT) < nb) {
            __builtin_amdgcn_s_sleep(1);
        }
        __threadfence();  // acquire: see other blocks' writes
    }
    __syncthreads();
}

// ===== Kernel A: attn logits -> softmax -> attn apply -> combine -> GRU =====
__global__ void __launch_bounds__(NT_A, 4) k_prefix(
    const int* x, const float* h, const float* enc, const float* emb,
    const float* W_attn, const float* b_attn,
    const float* W_comb, const float* b_comb,
    const float* w_ih, const float* w_hh, const float* b_ih, const float* b_hh,
    float* out_h, float* out_attn,
    float* logits128, float* attn_applied, float* g_vec,
    unsigned* bar)
{
    const int bid = blockIdx.x, t = threadIdx.x;
    const int lane = t & 63, wid = t >> 6;
    const int gw = bid * 4 + wid;          // global wave id, 0..1023
    const float4* e4 = (const float4*)(emb + (long long)x[0] * H);
    const float4* h4 = (const float4*)h;

    // ---- P1: logits[row] = dot(concat(e,h0), W_attn[row]) + b_attn[row]; one wave per row
    if (gw < MAXLEN) {
        const float4* w4 = (const float4*)(W_attn + gw * (2 * H));
        float acc = 0.f;
        #pragma unroll
        for (int i = 0; i < 8; i++) {
            int idx = lane + i * 64;       // 512 float4 = 2048 floats
            float4 wv = w4[idx];
            float4 cv = (idx < 256) ? e4[idx] : h4[idx - 256];
            acc += dot4(wv, cv);
        }
        acc = wave_reduce_sum(acc);
        if (lane == 0) logits128[gw] = acc + b_attn[gw];
    }
    sw_barrier(&bar[0], NB_A);

    // ---- P2: softmax over 128 + attn_applied[j] = sum_k w[k]*enc[k][j]; blocks 0..3
    if (bid < H / NT_A) {
        __shared__ float buf[MAXLEN];
        __shared__ float wsm[MAXLEN];
        if (t < MAXLEN) buf[t] = logits128[t];
        __syncthreads();
        float m = -INFINITY;
        #pragma unroll 8
        for (int k = 0; k < MAXLEN; k++) m = fmaxf(m, buf[k]);
        if (t < MAXLEN) wsm[t] = expf(buf[t] - m);
        __syncthreads();
        float s = 0.f;
        #pragma unroll 8
        for (int k = 0; k < MAXLEN; k++) s += wsm[k];
        float inv = 1.f / s;
        int j = bid * NT_A + t;
        float acc = 0.f;
        #pragma unroll 8
        for (int k = 0; k < MAXLEN; k++) acc += wsm[k] * enc[k * H + j];
        attn_applied[j] = acc * inv;
        if (bid == 0 && t < MAXLEN) out_attn[t] = wsm[t] * inv;
    }
    sw_barrier(&bar[1], NB_A);

    // ---- P3: g[row] = relu(dot(concat(e, attn_applied), W_comb[row]) + b); one wave per row
    {
        int row = gw;  // 1024 rows
        const float4* w4 = (const float4*)(W_comb + (long long)row * (2 * H));
        const float4* a4 = (const float4*)attn_applied;
        float acc = 0.f;
        #pragma unroll
        for (int i = 0; i < 8; i++) {
            int idx = lane + i * 64;
            float4 wv = w4[idx];
            float4 cv = (idx < 256) ? e4[idx] : a4[idx - 256];
            acc += dot4(wv, cv);
        }
        acc = wave_reduce_sum(acc);
        if (lane == 0) g_vec[row] = fmaxf(acc + b_comb[row], 0.f);
    }
    sw_barrier(&bar[2], NB_A);

    // ---- P4: GRU, one wave per output j: 6 dots + gates -> h_new[j]
    {
        int j = gw;  // 1024 outputs
        const float4* g4 = (const float4*)g_vec;
        float4 vg[4], vh[4];
        #pragma unroll
        for (int i = 0; i < 4; i++) {
            int idx = lane + i * 64;
            vg[i] = g4[idx];
            vh[i] = h4[idx];
        }
        float a6[6];
        #pragma unroll
        for (int gt = 0; gt < 3; gt++) {
            const float4* wi = (const float4*)(w_ih + (long long)(j + gt * H) * H);
            const float4* wh = (const float4*)(w_hh + (long long)(j + gt * H) * H);
            float ai = 0.f, ah = 0.f;
            #pragma unroll
            for (int i = 0; i < 4; i++) {
                int idx = lane + i * 64;
                ai += dot4(wi[idx], vg[i]);
                ah += dot4(wh[idx], vh[i]);
            }
            a6[gt] = ai;
            a6[3 + gt] = ah;
        }
        #pragma unroll
        for (int k = 0; k < 6; k++) a6[k] = wave_reduce_sum(a6[k]);
        if (lane == 0) {
            float gi_r = a6[0] + b_ih[j];
            float gi_z = a6[1] + b_ih[j + H];
            float gi_n = a6[2] + b_ih[j + 2 * H];
            float gh_r = a6[3] + b_hh[j];
            float gh_z = a6[4] + b_hh[j + H];
            float gh_n = a6[5] + b_hh[j + 2 * H];
            float r = 1.f / (1.f + expf(-(gi_r + gh_r)));
            float z = 1.f / (1.f + expf(-(gi_z + gh_z)));
            float n = tanhf(gi_n + r * gh_n);
            out_h[j] = (1.f - z) * n + z * h[j];
        }
    }
}

// ===== Kernel B: out matvec (1 row/wave, 16 rows/block) + last-block LSE merge =====
__global__ void __launch_bounds__(NT_B, 2) k_project(
    const float* hn, const float* W_out, const float* b_out,
    float* out, float* pmax, float* psum, float* lse_c, unsigned* ticket)
{
    const int t = threadIdx.x;
    const int lane = t & 63, wid = t >> 6;
    const int row = blockIdx.x * ROWS_B + wid;
    __shared__ float lm[ROWS_B];
    __shared__ int islast;

    const float4* h4 = (const float4*)hn;
    float4 hreg[4];
    #pragma unroll
    for (int i = 0; i < 4; i++) hreg[i] = h4[lane + i * 64];

    float logit = -INFINITY;
    if (row < VOCAB) {
        const float4* w4 = (const float4*)(W_out + (long long)row * H);
        float acc = 0.f;
        #pragma unroll
        for (int i = 0; i < 4; i++) acc += dot4(w4[lane + i * 64], hreg[i]);
        acc = wave_reduce_sum(acc);
        if (lane == 0) { logit = acc + b_out[row]; out[row] = logit; }
    }
    if (lane == 0) lm[wid] = logit;
    __syncthreads();
    if (t == 0) {
        float m = -INFINITY;
        #pragma unroll
        for (int i = 0; i < ROWS_B; i++) m = fmaxf(m, lm[i]);
        float s = 0.f;
        #pragma unroll
        for (int i = 0; i < ROWS_B; i++)
            if (lm[i] != -INFINITY) s += expf(lm[i] - m);
        pmax[blockIdx.x] = m;
        psum[blockIdx.x] = s;
        __threadfence();  // release partials
        unsigned old = __hip_atomic_fetch_add(ticket, 1u, __ATOMIC_ACQ_REL, __HIP_MEMORY_SCOPE_AGENT);
        islast = (old == (unsigned)(gridDim.x - 1)) ? 1 : 0;
    }
    __syncthreads();
    if (islast) {
        __threadfence();  // acquire all partials
        __shared__ float red[ROWS_B];
        float m = -INFINITY;
        for (int i = t; i < NB_B; i += NT_B) m = fmaxf(m, pmax[i]);
        #pragma unroll
        for (int off = 32; off > 0; off >>= 1) m = fmaxf(m, __shfl_down(m, off));
        if (lane == 0) red[wid] = m;
        __syncthreads();
        if (t == 0) {
            float mm = red[0];
            #pragma unroll
            for (int i = 1; i < ROWS_B; i++) mm = fmaxf(mm, red[i]);
            red[0] = mm;
        }
        __syncthreads();
        float M = red[0];
        float s = 0.f;
        for (int i = t; i < NB_B; i += NT_B) s += psum[i] * expf(pmax[i] - M);
        s = wave_reduce_sum(s);
        __syncthreads();  // red[] reuse
        if (lane == 0) red[wid] = s;
        __syncthreads();
        if (t == 0) {
            float ss = 0.f;
            #pragma unroll
            for (int i = 0; i < ROWS_B; i++) ss += red[i];
            lse_c[0] = M + logf(ss);
        }
    }
}

// ===== Kernel C: out[v] -= c =====
__global__ void k_sub(float* out, const float* c) {
    int v = blockIdx.x * blockDim.x + threadIdx.x;
    if (v < VOCAB) out[v] -= c[0];
}

extern "C" void kernel_launch(void* const* d_in, const int* in_sizes, int n_in,
                              void* d_out, int out_size, void* d_ws, size_t ws_size,
                              hipStream_t stream) {
    const int*   x     = (const int*)d_in[0];
    const float* h     = (const float*)d_in[1];   // [1,1,H]
    const float* enc   = (const float*)d_in[2];   // [128,H]
    const float* emb   = (const float*)d_in[3];   // [VOCAB,H]
    const float* W_attn= (const float*)d_in[4];   // [128,2H]
    const float* b_attn= (const float*)d_in[5];
    const float* W_comb= (const float*)d_in[6];   // [H,2H]
    const float* b_comb= (const float*)d_in[7];
    const float* w_ih  = (const float*)d_in[8];   // [3H,H]
    const float* w_hh  = (const float*)d_in[9];
    const float* b_ih  = (const float*)d_in[10];
    const float* b_hh  = (const float*)d_in[11];
    const float* W_out = (const float*)d_in[12];  // [VOCAB,H]
    const float* b_out = (const float*)d_in[13];

    float* out      = (float*)d_out;              // [VOCAB] log-probs
    float* out_h    = out + VOCAB;                // [H] h_new
    float* out_attn = out + VOCAB + H;            // [128] attn_w

    float* ws          = (float*)d_ws;
    float* logits128   = ws;            // 128
    float* attn_applied= ws + 256;      // 1024
    float* g_vec       = ws + 1280;     // 1024
    float* lse_c       = ws + 2304;     // 1
    float* pmax        = ws + 4096;     // NB_B (3142)
    float* psum        = ws + 8192;     // NB_B
    unsigned* bar      = (unsigned*)((char*)d_ws + 65536);  // bar[0..2], ticket at bar[3]

    // Zero the 3 barrier counters + the ticket (16 bytes) each call.
    hipMemsetAsync((void*)bar, 0, 16, stream);

    k_prefix<<<NB_A, NT_A, 0, stream>>>(x, h, enc, emb, W_attn, b_attn,
                                        W_comb, b_comb, w_ih, w_hh, b_ih, b_hh,
                                        out_h, out_attn,
                                        logits128, attn_applied, g_vec, bar);
    k_project<<<NB_B, NT_B, 0, stream>>>(out_h, W_out, b_out,
                                         out, pmax, psum, lse_c, &bar[3]);
    k_sub<<<(VOCAB + 1023) / 1024, 1024, 0, stream>>>(out, lse_c);
}

// Round 6
// 71.313 us; speedup vs baseline: 6.5327x; 3.9718x over previous
//
#include <hip/hip_runtime.h>
#include <math.h>

#define H 1024
#define MAXLEN 128
#define VOCAB 50257

#define ROWS_PB 8                                   // projection: rows per block (2 per wave)
#define NB_OUT ((VOCAB + ROWS_PB - 1) / ROWS_PB)    // 6283 blocks

__device__ inline float wave_reduce_sum(float v) {
    #pragma unroll
    for (int off = 32; off > 0; off >>= 1) v += __shfl_down(v, off);
    return v;  // lane 0 holds the sum
}

__device__ inline float dot4(float4 a, float4 b) {
    return a.x * b.x + a.y * b.y + a.z * b.z + a.w * b.w;
}

// K1: attn logits; one wave per row, 32 blocks x 256
__global__ void k_attn_logits(const int* x, const float* h, const float* emb,
                              const float* W_attn, const float* b_attn, float* logits) {
    const int lane = threadIdx.x & 63, wid = threadIdx.x >> 6;
    const int row = blockIdx.x * 4 + wid;   // 0..127
    const float4* w4 = (const float4*)(W_attn + row * (2 * H));
    const float4* e4 = (const float4*)(emb + (long long)x[0] * H);
    const float4* h4 = (const float4*)h;
    float acc = 0.f;
    #pragma unroll
    for (int i = 0; i < 8; i++) {
        int idx = lane + i * 64;            // 512 float4 = 2048 floats
        float4 wv = w4[idx];
        float4 cv = (idx < 256) ? e4[idx] : h4[idx - 256];
        acc += dot4(wv, cv);
    }
    acc = wave_reduce_sum(acc);
    if (lane == 0) logits[row] = acc + b_attn[row];
}

// K2: redundant softmax(128) per block + attn_applied[j] = sum_k w[k]*enc[k][j]
// 8 blocks x 256: block b handles columns [b*128, b*128+128)
__global__ void k_attn_sm_apply(const float* logits, const float* enc,
                                float* attn_applied, float* out_attn) {
    __shared__ float buf[MAXLEN];
    __shared__ float wsm[MAXLEN];
    int t = threadIdx.x;
    if (t < MAXLEN) buf[t] = logits[t];
    __syncthreads();
    float m = -INFINITY;
    #pragma unroll 8
    for (int k = 0; k < MAXLEN; k++) m = fmaxf(m, buf[k]);
    if (t < MAXLEN) wsm[t] = expf(buf[t] - m);
    __syncthreads();
    float s = 0.f;
    #pragma unroll 8
    for (int k = 0; k < MAXLEN; k++) s += wsm[k];
    float inv = 1.f / s;
    if (t < MAXLEN) {                        // 128 active threads per block
        int j = blockIdx.x * MAXLEN + t;
        float acc = 0.f;
        #pragma unroll 8
        for (int k = 0; k < MAXLEN; k++) acc += wsm[k] * enc[k * H + j];
        attn_applied[j] = acc * inv;
        if (blockIdx.x == 0) out_attn[t] = wsm[t] * inv;
    }
}

// K3: g[row] = relu(dot(concat(e, attn_applied), W_comb[row]) + b); one wave per row
__global__ void k_combine(const int* x, const float* emb, const float* attn_applied,
                          const float* W_comb, const float* b_comb, float* g) {
    int wid = threadIdx.x >> 6, lane = threadIdx.x & 63;
    int row = blockIdx.x * 4 + wid;
    const float4* w4 = (const float4*)(W_comb + (long long)row * (2 * H));
    const float4* e4 = (const float4*)(emb + (long long)x[0] * H);
    const float4* a4 = (const float4*)attn_applied;
    float acc = 0.f;
    #pragma unroll
    for (int i = 0; i < 8; i++) {
        int idx = lane + i * 64;
        float4 wv = w4[idx];
        float4 cv = (idx < 256) ? e4[idx] : a4[idx - 256];
        acc += dot4(wv, cv);
    }
    acc = wave_reduce_sum(acc);
    if (lane == 0) g[row] = fmaxf(acc + b_comb[row], 0.f);
}

// K4: fused GRU: block j computes all 6 dots + gates -> h_new[j]; 1024 blocks x 256
__global__ void k_gru_fused(const float* g, const float* h,
                            const float* w_ih, const float* w_hh,
                            const float* b_ih, const float* b_hh, float* h_new) {
    const int j = blockIdx.x, t = threadIdx.x;
    const int lane = t & 63, wid = t >> 6;
    __shared__ float red6[4][6];
    const float4* g4 = (const float4*)g;
    const float4* h4 = (const float4*)h;
    float4 vg = g4[t];
    float4 vh = h4[t];
    float a6[6];
    #pragma unroll
    for (int gt = 0; gt < 3; gt++) {
        const float4* wi = (const float4*)(w_ih + (long long)(j + gt * H) * H);
        const float4* wh = (const float4*)(w_hh + (long long)(j + gt * H) * H);
        a6[gt]     = dot4(wi[t], vg);
        a6[3 + gt] = dot4(wh[t], vh);
    }
    #pragma unroll
    for (int k = 0; k < 6; k++) {
        float v = a6[k];
        #pragma unroll
        for (int off = 32; off > 0; off >>= 1) v += __shfl_down(v, off);
        if (lane == 0) red6[wid][k] = v;
    }
    __syncthreads();
    if (t == 0) {
        float d[6];
        #pragma unroll
        for (int k = 0; k < 6; k++)
            d[k] = red6[0][k] + red6[1][k] + red6[2][k] + red6[3][k];
        float gi_r = d[0] + b_ih[j];
        float gi_z = d[1] + b_ih[j + H];
        float gi_n = d[2] + b_ih[j + 2 * H];
        float gh_r = d[3] + b_hh[j];
        float gh_z = d[4] + b_hh[j + H];
        float gh_n = d[5] + b_hh[j + 2 * H];
        float r = 1.f / (1.f + expf(-(gi_r + gh_r)));
        float z = 1.f / (1.f + expf(-(gi_z + gh_z)));
        float n = tanhf(gi_n + r * gh_n);
        h_new[j] = (1.f - z) * n + z * h[j];
    }
}

// K5: projection; 2 rows per wave (8 outstanding float4 loads), 8 rows/block.
// Per-block (max, sumexp) partials via plain stores (kernel boundary = sync).
__global__ void k_out_matvec(const float* hn, const float* W_out, const float* b_out,
                             float* out, float* pmax, float* psum) {
    const int t = threadIdx.x;
    const int lane = t & 63, wid = t >> 6;
    const int row0 = blockIdx.x * ROWS_PB + wid * 2;
    __shared__ float lm[ROWS_PB];

    const float4* h4 = (const float4*)hn;
    float4 hreg[4];
    #pragma unroll
    for (int i = 0; i < 4; i++) hreg[i] = h4[lane + i * 64];

    float l0 = -INFINITY, l1 = -INFINITY;
    if (row0 + 1 < VOCAB) {
        const float4* w0 = (const float4*)(W_out + (long long)row0 * H);
        const float4* w1 = (const float4*)(W_out + (long long)(row0 + 1) * H);
        float4 a0[4], a1[4];
        #pragma unroll
        for (int i = 0; i < 4; i++) a0[i] = w0[lane + i * 64];
        #pragma unroll
        for (int i = 0; i < 4; i++) a1[i] = w1[lane + i * 64];
        float acc0 = 0.f, acc1 = 0.f;
        #pragma unroll
        for (int i = 0; i < 4; i++) { acc0 += dot4(a0[i], hreg[i]); acc1 += dot4(a1[i], hreg[i]); }
        acc0 = wave_reduce_sum(acc0);
        acc1 = wave_reduce_sum(acc1);
        if (lane == 0) {
            l0 = acc0 + b_out[row0];
            l1 = acc1 + b_out[row0 + 1];
            out[row0] = l0;
            out[row0 + 1] = l1;
        }
    } else {
        // tail: handle remaining rows one at a time
        for (int r = row0; r < VOCAB && r < row0 + 2; r++) {
            const float4* w4 = (const float4*)(W_out + (long long)r * H);
            float acc = 0.f;
            #pragma unroll
            for (int i = 0; i < 4; i++) acc += dot4(w4[lane + i * 64], hreg[i]);
            acc = wave_reduce_sum(acc);
            if (lane == 0) {
                float lv = acc + b_out[r];
                out[r] = lv;
                if (r == row0) l0 = lv; else l1 = lv;
            }
        }
    }
    if (lane == 0) { lm[wid * 2] = l0; lm[wid * 2 + 1] = l1; }
    __syncthreads();
    if (t == 0) {
        float m = -INFINITY;
        #pragma unroll
        for (int i = 0; i < ROWS_PB; i++) m = fmaxf(m, lm[i]);
        float s = 0.f;
        #pragma unroll
        for (int i = 0; i < ROWS_PB; i++)
            if (lm[i] != -INFINITY) s += expf(lm[i] - m);
        pmax[blockIdx.x] = m;
        psum[blockIdx.x] = s;
    }
}

// K6: merge per-block partials -> c = M + log(sum_b s_b * exp(m_b - M))
__global__ void k_lse_merge(const float* pmax, const float* psum, float* c) {
    __shared__ float red[16];
    __shared__ float Msh;
    int lane = threadIdx.x & 63, wid = threadIdx.x >> 6;
    float m = -INFINITY;
    for (int i = threadIdx.x; i < NB_OUT; i += blockDim.x) m = fmaxf(m, pmax[i]);
    #pragma unroll
    for (int off = 32; off > 0; off >>= 1) m = fmaxf(m, __shfl_down(m, off));
    if (lane == 0) red[wid] = m;
    __syncthreads();
    if (threadIdx.x == 0) {
        float mm = red[0];
        for (int i = 1; i < 16; i++) mm = fmaxf(mm, red[i]);
        Msh = mm;
    }
    __syncthreads();
    float M = Msh;
    float s = 0.f;
    for (int i = threadIdx.x; i < NB_OUT; i += blockDim.x) s += psum[i] * expf(pmax[i] - M);
    s = wave_reduce_sum(s);
    if (lane == 0) red[wid] = s;
    __syncthreads();
    if (threadIdx.x == 0) {
        float ss = 0.f;
        for (int i = 0; i < 16; i++) ss += red[i];
        c[0] = M + logf(ss);
    }
}

// K7: out[v] -= c
__global__ void k_sub(float* out, const float* c) {
    int v = blockIdx.x * blockDim.x + threadIdx.x;
    if (v < VOCAB) out[v] -= c[0];
}

extern "C" void kernel_launch(void* const* d_in, const int* in_sizes, int n_in,
                              void* d_out, int out_size, void* d_ws, size_t ws_size,
                              hipStream_t stream) {
    const int*   x     = (const int*)d_in[0];
    const float* h     = (const float*)d_in[1];   // [1,1,H]
    const float* enc   = (const float*)d_in[2];   // [128,H]
    const float* emb   = (const float*)d_in[3];   // [VOCAB,H]
    const float* W_attn= (const float*)d_in[4];   // [128,2H]
    const float* b_attn= (const float*)d_in[5];
    const float* W_comb= (const float*)d_in[6];   // [H,2H]
    const float* b_comb= (const float*)d_in[7];
    const float* w_ih  = (const float*)d_in[8];   // [3H,H]
    const float* w_hh  = (const float*)d_in[9];
    const float* b_ih  = (const float*)d_in[10];
    const float* b_hh  = (const float*)d_in[11];
    const float* W_out = (const float*)d_in[12];  // [VOCAB,H]
    const float* b_out = (const float*)d_in[13];

    float* out      = (float*)d_out;              // [VOCAB] log-probs
    float* out_h    = out + VOCAB;                // [H] h_new
    float* out_attn = out + VOCAB + H;            // [128] attn_w

    float* ws          = (float*)d_ws;
    float* logits128   = ws;            // 128
    float* attn_applied= ws + 256;      // 1024
    float* g_vec       = ws + 1280;     // 1024
    float* lse_c       = ws + 2304;     // 1
    float* pmax        = ws + 4096;     // NB_OUT (6283)
    float* psum        = ws + 12288;    // NB_OUT

    k_attn_logits<<<MAXLEN / 4, 256, 0, stream>>>(x, h, emb, W_attn, b_attn, logits128);
    k_attn_sm_apply<<<H / MAXLEN, 256, 0, stream>>>(logits128, enc, attn_applied, out_attn);
    k_combine<<<H / 4, 256, 0, stream>>>(x, emb, attn_applied, W_comb, b_comb, g_vec);
    k_gru_fused<<<H, 256, 0, stream>>>(g_vec, h, w_ih, w_hh, b_ih, b_hh, out_h);
    k_out_matvec<<<NB_OUT, 256, 0, stream>>>(out_h, W_out, b_out, out, pmax, psum);
    k_lse_merge<<<1, 1024, 0, stream>>>(pmax, psum, lse_c);
    k_sub<<<(VOCAB + 1023) / 1024, 1024, 0, stream>>>(out, lse_c);
}